// Round 2
// baseline (176.801 us; speedup 1.0000x reference)
//
#include <hip/hip_runtime.h>
#include <hip/hip_bf16.h>

// EmotionCaps dynamic routing (fp32 I/O per reference):
// u: [B=64, N=1024, I=64] f32; W: [N=1024, E=8, O=32, I=64] f32
// out: v [B=64, E=8, O=32] f32
// u_hat[b,n,e,o] = sum_i W[n,e,o,i]*u[b,n,i]; 3 routing iterations.
// u_hat stored bf16 in workspace (32 MB) — 2% absmax threshold permits.

#define B_  64
#define N_  1024
#define I_  64
#define E_  8
#define O_  32
#define EO_ 256

__device__ __forceinline__ float bf2f(unsigned int h) {
    unsigned int u = (h & 0xffffu) << 16;
    return __builtin_bit_cast(float, u);
}
__device__ __forceinline__ unsigned short f2bf(float f) {
    unsigned int u = __builtin_bit_cast(unsigned int, f);
    unsigned int r = u + 0x7fffu + ((u >> 16) & 1u);   // round-to-nearest-even
    return (unsigned short)(r >> 16);
}

// ---------------------------------------------------------------------------
// K1: u_hat[b,n,eo] = dot(W[n,eo,:], u[b,n,:]).  One workgroup per n.
// LDS: u[:,n,:] fp32 (16KB). W row (n,eo=t,:) read direct from global
// (16 float4 per thread; the block's loop covers W[n] = 64KB contiguous).
// Thread t owns output column eo=t for all 64 b's.
// ---------------------------------------------------------------------------
__global__ __launch_bounds__(256) void k_uhat(const float* __restrict__ u,
                                              const float* __restrict__ W,
                                              unsigned short* __restrict__ uh) {
    const int n = blockIdx.x;
    const int t = threadIdx.x;
    __shared__ __align__(16) float ul[B_ * I_];   // 16 KB fp32

    // stage u[:, n, :]: 64 rows x 64 fp32 = 1024 float4
#pragma unroll
    for (int j = 0; j < 4; ++j) {
        int idx = t + 256 * j;                 // 0..1023
        int b = idx >> 4, c = idx & 15;        // 16 float4 per 64-float row
        ((float4*)ul)[idx] =
            *(const float4*)(u + (size_t)b * (N_ * I_) + n * I_ + c * 4);
    }

    // this thread's W row -> 64 fp32 regs (before the barrier: independent)
    float w[I_];
    {
        const float4* wr = (const float4*)(W + (size_t)n * (EO_ * I_) + t * I_);
#pragma unroll
        for (int c = 0; c < 16; ++c) {
            float4 q = wr[c];
            w[4 * c + 0] = q.x; w[4 * c + 1] = q.y;
            w[4 * c + 2] = q.z; w[4 * c + 3] = q.w;
        }
    }
    __syncthreads();

#pragma unroll 1
    for (int bb = 0; bb < 8; ++bb) {
        float acc[8];
#pragma unroll
        for (int j = 0; j < 8; ++j) acc[j] = 0.f;
#pragma unroll
        for (int b8 = 0; b8 < 8; ++b8) {
            const float4* ur = (const float4*)&ul[(bb * 8 + b8) * I_];
#pragma unroll
            for (int iq = 0; iq < 16; ++iq) {
                float4 uu = ur[iq];   // broadcast LDS read (uniform addr)
                acc[b8] = fmaf(w[iq * 4 + 0], uu.x, acc[b8]);
                acc[b8] = fmaf(w[iq * 4 + 1], uu.y, acc[b8]);
                acc[b8] = fmaf(w[iq * 4 + 2], uu.z, acc[b8]);
                acc[b8] = fmaf(w[iq * 4 + 3], uu.w, acc[b8]);
            }
        }
#pragma unroll
        for (int b8 = 0; b8 < 8; ++b8) {
            uh[(size_t)(bb * 8 + b8) * (N_ * EO_) + n * EO_ + t] = f2bf(acc[b8]);
        }
    }
}

// ---------------------------------------------------------------------------
// K2: one routing pass over u_hat. Barrier-free in-wave:
//   lane l owns eo = 4l..4l+3  (e = l>>3, o = (l&7)*4 .. +3)
//   uv[e]   : shfl_xor 1,2,4  (sum over o within 8-lane e-group)
//   softmax : shfl_xor 8,16,32 (max+sum over the 8 e-groups in the wave)
// mode 0: c = 1/8 (softmax of zero logits), no v needed
// mode 1: logits = uv (b was 0), write b_ws
// mode 2: logits = b_ws + uv (final pass, no write)
// s accumulated fp32: LDS cross-wave reduce + 1 atomicAdd per (b,eo) per wg.
// ---------------------------------------------------------------------------
__global__ __launch_bounds__(256) void k_route(const unsigned short* __restrict__ uh,
                                               const float* __restrict__ vws,
                                               float* __restrict__ bws,
                                               float* __restrict__ s,
                                               int mode) {
    const int wg = blockIdx.x;
    const int b = wg >> 4, chunk = wg & 15;
    const int t = threadIdx.x, wave = t >> 6, l = t & 63;
    const int e = l >> 3;

    float4 v4 = make_float4(0.f, 0.f, 0.f, 0.f);
    if (mode != 0) v4 = *(const float4*)(vws + b * EO_ + 4 * l);

    float a0 = 0.f, a1 = 0.f, a2 = 0.f, a3 = 0.f;
    const int n0 = chunk * 64 + wave * 16;
#pragma unroll 1
    for (int nn = 0; nn < 16; ++nn) {
        const int n = n0 + nn;
        uint2 p = *(const uint2*)(uh + (size_t)b * (N_ * EO_) + n * EO_ + 4 * l);
        float x0 = bf2f(p.x), x1 = bf2f(p.x >> 16);
        float x2 = bf2f(p.y), x3 = bf2f(p.y >> 16);
        float c;
        if (mode == 0) {
            c = 0.125f;
        } else {
            float pd = x0 * v4.x + x1 * v4.y + x2 * v4.z + x3 * v4.w;
            pd += __shfl_xor(pd, 1);
            pd += __shfl_xor(pd, 2);
            pd += __shfl_xor(pd, 4);          // uv[e] in all 8 lanes of group
            float logit = pd;
            if (mode == 2) {
                logit += bws[b * (N_ * E_) + n * E_ + e];
            } else if ((l & 7) == 0) {
                bws[b * (N_ * E_) + n * E_ + e] = logit;
            }
            float m = logit;
            m = fmaxf(m, __shfl_xor(m, 8));
            m = fmaxf(m, __shfl_xor(m, 16));
            m = fmaxf(m, __shfl_xor(m, 32));
            float ex = __expf(logit - m);
            float sm = ex;
            sm += __shfl_xor(sm, 8);
            sm += __shfl_xor(sm, 16);
            sm += __shfl_xor(sm, 32);
            c = ex / sm;
        }
        a0 = fmaf(c, x0, a0);
        a1 = fmaf(c, x1, a1);
        a2 = fmaf(c, x2, a2);
        a3 = fmaf(c, x3, a3);
    }

    __shared__ __align__(16) float red[4][EO_];
    *(float4*)&red[wave][4 * l] = make_float4(a0, a1, a2, a3);
    __syncthreads();
    float tot = red[0][t] + red[1][t] + red[2][t] + red[3][t];
    atomicAdd(&s[b * EO_ + t], tot);
}

// ---------------------------------------------------------------------------
// K3: v = squash(s) over o; re-zero s for next pass; final pass writes f32 out
// ---------------------------------------------------------------------------
__global__ __launch_bounds__(256) void k_squash(float* __restrict__ s,
                                                float* __restrict__ vws,
                                                float* __restrict__ out,
                                                int final_) {
    const int b = blockIdx.x, t = threadIdx.x;   // t = eo
    float sv = s[b * EO_ + t];
    float sq = sv * sv;
    sq += __shfl_xor(sq, 1);
    sq += __shfl_xor(sq, 2);
    sq += __shfl_xor(sq, 4);
    sq += __shfl_xor(sq, 8);
    sq += __shfl_xor(sq, 16);                    // norm^2 over the 32-lane o-group
    float nrm = sqrtf(sq);
    float scale = sq / ((1.f + sq) * (nrm + 1e-8f));
    float vv = scale * sv;
    vws[b * EO_ + t] = vv;
    s[b * EO_ + t] = 0.f;
    if (final_) out[b * EO_ + t] = vv;
}

__global__ void k_zero(float* __restrict__ s) {
    s[blockIdx.x * 256 + threadIdx.x] = 0.f;
}

extern "C" void kernel_launch(void* const* d_in, const int* in_sizes, int n_in,
                              void* d_out, int out_size, void* d_ws, size_t ws_size,
                              hipStream_t stream) {
    const float* u = (const float*)d_in[0];     // f32 [64,1024,64]
    const float* W = (const float*)d_in[1];     // f32 [1024,8,32,64]
    float* out = (float*)d_out;                 // f32 [64,8,32]

    char* ws = (char*)d_ws;
    unsigned short* uh = (unsigned short*)ws;            // 33,554,432 B  u_hat bf16
    float* bws = (float*)(ws + 33554432);                //  2,097,152 B  logits fp32
    float* s   = (float*)(ws + 35651584);                //     65,536 B
    float* vws = (float*)(ws + 35717120);                //     65,536 B

    k_zero  <<<dim3(B_),   dim3(256), 0, stream>>>(s);
    k_uhat  <<<dim3(N_),   dim3(256), 0, stream>>>(u, W, uh);
    k_route <<<dim3(1024), dim3(256), 0, stream>>>(uh, vws, bws, s, 0);
    k_squash<<<dim3(B_),   dim3(256), 0, stream>>>(s, vws, out, 0);
    k_route <<<dim3(1024), dim3(256), 0, stream>>>(uh, vws, bws, s, 1);
    k_squash<<<dim3(B_),   dim3(256), 0, stream>>>(s, vws, out, 0);
    k_route <<<dim3(1024), dim3(256), 0, stream>>>(uh, vws, bws, s, 2);
    k_squash<<<dim3(B_),   dim3(256), 0, stream>>>(s, vws, out, 1);
}